// Round 5
// baseline (453.116 us; speedup 1.0000x reference)
//
#include <hip/hip_runtime.h>
#include <hip/hip_bf16.h>
#include <math.h>

// N=500,000 nodes, E=16,000,000 edges, D_COEF=1, EPS=1e-12.
// Outputs (fp32, flat): v [N,2] then torque [N,1].
// torque = w0 * sum_sin / max(||sum||, eps)  (count cancels in normalize).
//
// R2: global fp32 atomics -> binning. R3: two-phase -> 408 us.
// R4: LDS counting-sort writeout + packed u64 LDS atomics -> 278 us.
// R5: theta_q carried in entry -> 264 us (BEST). Phase1=145, phase2=119.
// R6 FAILED: 1024thr -> 16 VGPR + spills. More waves != faster.
// R7 FAILED: gather->phase2 (+75 there, -0 in p1: gather was hidden);
//     nt stores amplified writes.
// R8 FAILED: rtn-atomic rank capture (lcnt removed): 207 us. DS-atomic
//     throughput theory dead.
// => All pipes <15% busy, waves don't help, atomics don't matter:
//     phase 1 is CRITICAL-PATH LATENCY bound (load->gather->barrier->
//     cursor-atomic chain, ~2 resident blocks).
// R9: persistent blocks + software pipeline (prefetch next chunk's
//     src/dst under B-E, gather next theta after B, defer gbase write).
//     Infra failure -- no data. R10: same algorithm, ping-pong register
//     state via unrolled parity loop (no rotation copies, lower VGPR).
//
// ws layout: [0..256) uint cursors (1 KB), then uint bins[NB * CAP].

#define NBITS_Q   21
#define Q_MASK    ((1u << NBITS_Q) - 1)
#define Q_SCALE   131072.0f            // 2^21 / 16
#define Q_INV     (1.0f / 131072.0f)
#define BIN_SHIFT 11
#define BIN_W     2048
#define NB        245                  // ceil(500000/2048)
#define CAP       67584                // mean 65306 + ~9 sigma, mult of 4
#define K_BATCH   4096                 // edges per phase-1 chunk
#define EPT       16                   // edges per thread, phase 1
#define NBLK_P1   768                  // persistent phase-1 blocks (3/CU)
#define SCALE_F   524288.0f            // 2^19 (phase-2 fixed-point)
#define INV_SCALE (1.0f / 524288.0f)
#define INV_2PI   0.15915494309189535f

typedef unsigned uint4_v __attribute__((ext_vector_type(4)));

__global__ void init_cursors(unsigned* __restrict__ cur) {
    int b = blockIdx.x * blockDim.x + threadIdx.x;
    if (b < 256) cur[b] = (b < NB) ? (unsigned)b * CAP : 0u;
}

__global__ __launch_bounds__(256) void bin_edges_sort(
        const float* __restrict__ theta,
        const int4* __restrict__ src4, const int4* __restrict__ dst4,
        unsigned* __restrict__ bins, unsigned* __restrict__ cursor, int E)
{
    __shared__ unsigned      sorted[K_BATCH];   // 16 KB
    __shared__ unsigned char sbin[K_BATCH];     //  4 KB
    __shared__ unsigned      hist[256];
    __shared__ unsigned      base_[256];
    __shared__ unsigned      gbase[256];
    __shared__ unsigned      lcnt[256];

    const int tid    = threadIdx.x;
    const int E4     = E >> 2;
    const int NCHUNK = (E + K_BATCH - 1) / K_BATCH;   // 3907

    hist[tid] = 0u;
    lcnt[tid] = 0u;

    // ping-pong register state: parity A holds chunk c, parity Z chunk c+1
    int4  dQA[EPT / 4], dQZ[EPT / 4];
    float tqA[EPT],     tqZ[EPT];

    // ---- prologue: load + gather chunk c0 into parity A ----
    int c = blockIdx.x;
    {
        int4 sQ[EPT / 4];
        const int cb4 = c * (K_BATCH >> 2);
#pragma unroll
        for (int j = 0; j < EPT / 4; ++j) {
            const int idx4 = cb4 + j * 256 + tid;
            if (idx4 < E4) { sQ[j] = src4[idx4]; dQA[j] = dst4[idx4]; }
            else           { sQ[j] = make_int4(0,0,0,0); dQA[j] = make_int4(0,0,0,0); }
        }
#pragma unroll
        for (int j = 0; j < EPT / 4; ++j) {
            tqA[j * 4 + 0] = theta[sQ[j].x];
            tqA[j * 4 + 1] = theta[sQ[j].y];
            tqA[j * 4 + 2] = theta[sQ[j].z];
            tqA[j * 4 + 3] = theta[sQ[j].w];
        }
    }
    __syncthreads();   // hist/lcnt zero visible

    bool done = false;
    while (!done) {
#pragma unroll
        for (int par = 0; par < 2; ++par) {
            int4*  dQ  = (par == 0) ? dQA : dQZ;      // compile-time select
            float* tq  = (par == 0) ? tqA : tqZ;
            int4*  dQn = (par == 0) ? dQZ : dQA;
            float* tqn = (par == 0) ? tqZ : tqA;

            if (done) continue;

            const int cn = c + NBLK_P1;

            // ---- issue next chunk's src+dst loads (overlap B-E) ----
            int4 sQn[EPT / 4];
            const bool have_next = (cn < NCHUNK);
            if (have_next) {
                const int nb4 = cn * (K_BATCH >> 2);
#pragma unroll
                for (int j = 0; j < EPT / 4; ++j) {
                    const int idx4 = nb4 + j * 256 + tid;
                    if (idx4 < E4) { sQn[j] = src4[idx4]; dQn[j] = dst4[idx4]; }
                    else { sQn[j] = make_int4(0,0,0,0); dQn[j] = make_int4(0,0,0,0); }
                }
            }

            // ---- B: build entries, histogram (no-return atomics) ----
            const int cb4 = c * (K_BATCH >> 2);
            unsigned ent[EPT];
            unsigned bn[EPT];          // bin id, 0xFF = invalid
#pragma unroll
            for (int j = 0; j < EPT / 4; ++j) {
                const int idx4 = cb4 + j * 256 + tid;
                const int q0   = j * 4;
                if (idx4 < E4) {
                    const int dd[4] = {dQ[j].x, dQ[j].y, dQ[j].z, dQ[j].w};
#pragma unroll
                    for (int k = 0; k < 4; ++k) {
                        const unsigned b = (unsigned)dd[k] >> BIN_SHIFT;
                        float qf = (tq[q0 + k] + 8.0f) * Q_SCALE + 0.5f;
                        qf = fminf(fmaxf(qf, 0.0f), 2097151.0f);
                        ent[q0 + k] = ((unsigned)(dd[k] & (BIN_W - 1)) << NBITS_Q)
                                      | (unsigned)qf;
                        bn[q0 + k]  = b;
                        atomicAdd(&hist[b], 1u);
                    }
                } else {
#pragma unroll
                    for (int k = 0; k < 4; ++k) bn[q0 + k] = 0xFFu;
                }
            }
            __syncthreads();

            // ---- gather next chunk's theta (sQn arrived during B) ----
            if (have_next) {
#pragma unroll
                for (int j = 0; j < EPT / 4; ++j) {
                    tqn[j * 4 + 0] = theta[sQn[j].x];
                    tqn[j * 4 + 1] = theta[sQn[j].y];
                    tqn[j * 4 + 2] = theta[sQn[j].z];
                    tqn[j * 4 + 3] = theta[sQn[j].w];
                }
            }

            // ---- C: single-wave scan + cursor reserve (gb in regs) ----
            unsigned hC[4], gbC[4];
            if (tid < 64) {
#pragma unroll
                for (int k = 0; k < 4; ++k) hC[k] = hist[tid * 4 + k];
                const unsigned tot = hC[0] + hC[1] + hC[2] + hC[3];
                unsigned s = tot;
#pragma unroll
                for (int off = 1; off < 64; off <<= 1) {
                    const unsigned y = __shfl_up(s, off);
                    if (tid >= off) s += y;
                }
                unsigned run = s - tot;      // exclusive across lanes
#pragma unroll
                for (int k = 0; k < 4; ++k) {
                    base_[tid * 4 + k] = run;
                    run += hC[k];
                }
#pragma unroll
                for (int k = 0; k < 4; ++k)
                    gbC[k] = hC[k] ? atomicAdd(&cursor[tid * 4 + k], hC[k]) : 0u;
            }
            __syncthreads();

            // ---- D: scatter (lcnt rtn atomics) + deferred gbase write ----
#pragma unroll
            for (int q = 0; q < EPT; ++q) {
                if (bn[q] != 0xFFu) {
                    const unsigned b   = bn[q];
                    const unsigned pos = base_[b] + atomicAdd(&lcnt[b], 1u);
                    sorted[pos] = ent[q];
                    sbin[pos]   = (unsigned char)b;
                }
            }
            if (tid < 64) {   // cursor-atomic latency hidden under scatter
#pragma unroll
                for (int k = 0; k < 4; ++k)
                    if (hC[k]) gbase[tid * 4 + k] = gbC[k];
            }
            __syncthreads();

            // ---- E: coalesced write-out + re-zero hist/lcnt ----
            const int nval = min(K_BATCH, E - c * K_BATCH);
            for (int l = tid; l < nval; l += 256) {
                const unsigned b    = sbin[l];
                const unsigned gpos = gbase[b] + ((unsigned)l - base_[b]);
                if (gpos < (b + 1u) * CAP)  // ~9-sigma overflow guard
                    bins[gpos] = sorted[l];
            }
            hist[tid] = 0u;
            lcnt[tid] = 0u;
            __syncthreads();

            c = cn;
            if (!have_next) done = true;
        }
    }
}

__global__ __launch_bounds__(1024) void reduce_bins(
        const float* __restrict__ theta, const unsigned* __restrict__ bins,
        const unsigned* __restrict__ cursor, const float* __restrict__ v0p,
        const float* __restrict__ w0p, float* __restrict__ out, int N)
{
    __shared__ float th[BIN_W];                         //  8 KB
    __shared__ unsigned long long acc[BIN_W];           // 16 KB
    const int b     = blockIdx.x;
    const int tid   = threadIdx.x;
    const int node0 = b * BIN_W;
    const int W     = min(BIN_W, N - node0);

    for (int j = tid; j < BIN_W; j += 1024) {
        th[j]  = (j < W) ? theta[node0 + j] : 0.f;
        acc[j] = 0ull;
    }
    __syncthreads();

    const unsigned  base  = (unsigned)b * CAP;
    const int       count = (int)(cursor[b] - base);
    const unsigned* bp    = bins + base;

    // stream 8 entries/thread/iter via two unit-stride nontemporal uint4 loads
    const int CH = 1024 * 8;
    int i0 = 0;
    for (; i0 + CH <= count; i0 += CH) {
        const uint4_v ea = __builtin_nontemporal_load(
            (const uint4_v*)(bp + i0 + tid * 4));
        const uint4_v eb = __builtin_nontemporal_load(
            (const uint4_v*)(bp + i0 + 4096 + tid * 4));
        const unsigned ee[8] = {ea.x, ea.y, ea.z, ea.w, eb.x, eb.y, eb.z, eb.w};
#pragma unroll
        for (int k = 0; k < 8; ++k) {
            const unsigned e = ee[k];
            const unsigned l = e >> NBITS_Q;
            const float ts = (float)(e & Q_MASK) * Q_INV - 8.0f;
            const float r  = (ts - th[l]) * INV_2PI;
            const float sn = __builtin_amdgcn_sinf(r);
            const float cs = __builtin_amdgcn_cosf(r);
            const unsigned cq = (unsigned)((cs + 1.0f) * SCALE_F + 0.5f);
            const unsigned sq = (unsigned)((sn + 1.0f) * SCALE_F + 0.5f);
            atomicAdd(&acc[l], (1ull << 56) | ((unsigned long long)cq << 28)
                               | (unsigned long long)sq);
        }
    }
    for (int i = i0 + tid; i < count; i += 1024) {
        const unsigned e = __builtin_nontemporal_load(bp + i);
        const unsigned l = e >> NBITS_Q;
        const float ts = (float)(e & Q_MASK) * Q_INV - 8.0f;
        const float r  = (ts - th[l]) * INV_2PI;
        const float sn = __builtin_amdgcn_sinf(r);
        const float cs = __builtin_amdgcn_cosf(r);
        const unsigned cq = (unsigned)((cs + 1.0f) * SCALE_F + 0.5f);
        const unsigned sq = (unsigned)((sn + 1.0f) * SCALE_F + 0.5f);
        atomicAdd(&acc[l], (1ull << 56) | ((unsigned long long)cq << 28)
                           | (unsigned long long)sq);
    }
    __syncthreads();

    // epilogue: unpack, v and torque (th[] is exact fp32 theta)
    const float v0 = *v0p, w0 = *w0p;
    for (int j = tid; j < W; j += 1024) {
        const float t  = th[j];
        const float rr = t * INV_2PI;
        const float sn = __builtin_amdgcn_sinf(rr);
        const float cs = __builtin_amdgcn_cosf(rr);
        ((float2*)out)[node0 + j] = make_float2(v0 * cs, v0 * sn);
        const unsigned long long P = acc[j];
        const float c  = (float)(unsigned)(P >> 56);
        const float xs = (float)(unsigned)((P >> 28) & 0xFFFFFFFull) * INV_SCALE - c;
        const float ys = (float)(unsigned)(P & 0xFFFFFFFull) * INV_SCALE - c;
        const float nrm = sqrtf(xs * xs + ys * ys);
        out[2 * N + node0 + j] = w0 * (ys / fmaxf(nrm, 1e-12f));
    }
}

// ---------- fallback path (round-2 kernels) if ws is too small ----------

__global__ void zero_ws_kernel(float4* __restrict__ ws, int n4) {
    int i = blockIdx.x * blockDim.x + threadIdx.x;
    if (i < n4) ws[i] = make_float4(0.f, 0.f, 0.f, 0.f);
}

__global__ void edge_kernel_fb(const float* __restrict__ theta,
                               const int4* __restrict__ src4,
                               const int4* __restrict__ dst4,
                               float2* __restrict__ acc, int E8) {
    int i = blockIdx.x * blockDim.x + threadIdx.x;
    if (i >= E8) return;
    const int4 s0 = src4[2 * i], s1 = src4[2 * i + 1];
    const int4 d0 = dst4[2 * i], d1 = dst4[2 * i + 1];
    const int ss[8] = {s0.x, s0.y, s0.z, s0.w, s1.x, s1.y, s1.z, s1.w};
    const int dd[8] = {d0.x, d0.y, d0.z, d0.w, d1.x, d1.y, d1.z, d1.w};
    float ts[8], td[8];
#pragma unroll
    for (int k = 0; k < 8; ++k) ts[k] = theta[ss[k]];
#pragma unroll
    for (int k = 0; k < 8; ++k) td[k] = theta[dd[k]];
#pragma unroll
    for (int k = 0; k < 8; ++k) {
        float sn, cs;
        __sincosf(ts[k] - td[k], &sn, &cs);
        atomicAdd(&acc[dd[k]].x, cs);
        atomicAdd(&acc[dd[k]].y, sn);
    }
}

__global__ void node_kernel_fb(const float* __restrict__ theta,
                               const float2* __restrict__ acc,
                               const float* __restrict__ v0p,
                               const float* __restrict__ w0p,
                               float* __restrict__ out, int N) {
    int i = blockIdx.x * blockDim.x + threadIdx.x;
    if (i >= N) return;
    const float v0 = *v0p, w0 = *w0p;
    float sn, cs;
    __sincosf(theta[i], &sn, &cs);
    ((float2*)out)[i] = make_float2(v0 * cs, v0 * sn);
    const float2 a = acc[i];
    const float nrm = sqrtf(a.x * a.x + a.y * a.y);
    out[2 * N + i] = w0 * (a.y / fmaxf(nrm, 1e-12f));
}

extern "C" void kernel_launch(void* const* d_in, const int* in_sizes, int n_in,
                              void* d_out, int out_size, void* d_ws, size_t ws_size,
                              hipStream_t stream) {
    const float* theta = (const float*)d_in[0];
    const int*   src   = (const int*)d_in[1];
    const int*   dst   = (const int*)d_in[2];
    const float* v0p   = (const float*)d_in[3];
    const float* w0p   = (const float*)d_in[4];
    float*       out   = (float*)d_out;

    const int N = in_sizes[0];   // 500,000
    const int E = in_sizes[1];   // 16,000,000

    const size_t need = 1024 + (size_t)NB * CAP * sizeof(unsigned);

    if (ws_size >= need && N <= NB * BIN_W) {
        unsigned* cursor = (unsigned*)d_ws;
        unsigned* bins   = cursor + 256;

        init_cursors<<<1, 256, 0, stream>>>(cursor);

        bin_edges_sort<<<NBLK_P1, 256, 0, stream>>>(theta, (const int4*)src,
                                                    (const int4*)dst,
                                                    bins, cursor, E);

        const int nbins = (N + BIN_W - 1) / BIN_W;      // 245
        reduce_bins<<<nbins, 1024, 0, stream>>>(theta, bins, cursor,
                                                v0p, w0p, out, N);
    } else {
        float2* acc = (float2*)d_ws;
        {
            const int n4 = (2 * N) / 4;
            zero_ws_kernel<<<(n4 + 255) / 256, 256, 0, stream>>>((float4*)d_ws, n4);
        }
        {
            const int E8 = E / 8;
            edge_kernel_fb<<<(E8 + 255) / 256, 256, 0, stream>>>(
                theta, (const int4*)src, (const int4*)dst, acc, E8);
        }
        node_kernel_fb<<<(N + 255) / 256, 256, 0, stream>>>(theta, acc, v0p, w0p,
                                                            out, N);
    }
}

// Round 6
// 355.879 us; speedup vs baseline: 1.2732x; 1.2732x over previous
//
#include <hip/hip_runtime.h>
#include <hip/hip_bf16.h>
#include <math.h>

// N=500,000 nodes, E=16,000,000 edges, D_COEF=1, EPS=1e-12.
// Outputs (fp32, flat): v [N,2] then torque [N,1].
//
// KEY IDENTITY (R11): sum over edges into d of (cos(ts-td), sin(ts-td))
// equals the rotation by -td of (C,S) = (sum cos ts, sum sin ts).
// Rotation preserves the norm, so
//   torque = w0 * (cos_td * S - sin_td * C) / max(||(C,S)||, eps).
// => per-edge work needs only table[src] = (cos ts, sin ts), gathered
// from a precomputed 4MB f32 table. 16M sincos -> 500K sincos.
//
// R5: theta_q in entry -> 264 us (phase1=145 proven local optimum).
// R6/R9/R10 FAILED: occupancy/pipeline experiments all contaminated by
//     codegen (spills / scratch from addressable arrays). Abandoned.
// R7: phase1 without gather == 145 us too (gather was free); nt STORES
//     amplify writes -> plain stores.
// R8 FAILED: rtn-atomic rank capture. R5 atomic structure kept.
// R11: phase2 was VALU-bound on per-edge sincos (350cy/8-entry group).
//     Entry = (local_dst:11 | src:19); phase2 = stream + 8B table
//     gather + pack + u64 LDS atomic. build_table also emits v output.
//
// ws layout (tier 1): float2 table[Npad] (4MB) | uint cursor[256] | bins.
// Tier 2 (ws too small): proven R5 kernels. Tier 3: global-atomic fb.

#define NBITS_S   19
#define SRC_MASK  ((1u << NBITS_S) - 1)
#define NBITS_Q   21
#define Q_MASK    ((1u << NBITS_Q) - 1)
#define Q_SCALE   131072.0f
#define Q_INV     (1.0f / 131072.0f)
#define BIN_SHIFT 11
#define BIN_W     2048
#define NB        245                  // ceil(500000/2048)
#define CAP       67584                // mean 65306 + ~9 sigma, mult of 4
#define K_BATCH   8192                 // edges per phase-1 block
#define EPT       32                   // edges per thread, phase 1
#define SCALE_F   524288.0f            // 2^19 fixed-point
#define INV_SCALE (1.0f / 524288.0f)
#define INV_2PI   0.15915494309189535f

typedef unsigned uint4_v __attribute__((ext_vector_type(4)));

__global__ void init_cursors(unsigned* __restrict__ cur) {
    int b = blockIdx.x * blockDim.x + threadIdx.x;
    if (b < 256) cur[b] = (b < NB) ? (unsigned)b * CAP : 0u;
}

// ---- phase 0: per-node (cos,sin) table + v output ----
__global__ __launch_bounds__(256) void build_table(
        const float* __restrict__ theta, const float* __restrict__ v0p,
        float2* __restrict__ table, float* __restrict__ out, int N)
{
    const int i = blockIdx.x * blockDim.x + threadIdx.x;
    if (i >= N) return;
    const float t = theta[i];
    float sn, cs;
    __sincosf(t, &sn, &cs);
    table[i] = make_float2(cs, sn);
    const float v0 = *v0p;
    ((float2*)out)[i] = make_float2(v0 * cs, v0 * sn);
}

// ---- phase 1 (tier 1): partition edges, entry = (local_dst:11|src:19) ----
__global__ __launch_bounds__(256) void bin_edges_sort_src(
        const int4* __restrict__ src4, const int4* __restrict__ dst4,
        unsigned* __restrict__ bins, unsigned* __restrict__ cursor, int E)
{
    __shared__ unsigned      sorted[K_BATCH];   // 32 KB
    __shared__ unsigned char sbin[K_BATCH];     //  8 KB
    __shared__ unsigned      hist[256];
    __shared__ unsigned      base[256];
    __shared__ unsigned      gbase[256];
    __shared__ unsigned      lcnt[256];

    const int tid   = threadIdx.x;
    const int bb    = blockIdx.x;
    const int e0    = bb * K_BATCH;
    const int nval  = min(K_BATCH, E - e0);
    const int E4    = E >> 2;
    const int base4 = e0 >> 2;

    hist[tid] = 0u;
    lcnt[tid] = 0u;
    __syncthreads();

    int4 sQ[EPT / 4], dQ[EPT / 4];
#pragma unroll
    for (int j = 0; j < EPT / 4; ++j) {
        const int idx4 = base4 + j * 256 + tid;
        if (idx4 < E4) { sQ[j] = src4[idx4]; dQ[j] = dst4[idx4]; }
        else           { sQ[j] = make_int4(0,0,0,0); dQ[j] = make_int4(0,0,0,0); }
    }

    unsigned ent[EPT];
    unsigned bn[EPT];
#pragma unroll
    for (int j = 0; j < EPT / 4; ++j) {
        const int idx4 = base4 + j * 256 + tid;
        const int q0   = j * 4;
        if (idx4 < E4) {
            const int dd[4] = {dQ[j].x, dQ[j].y, dQ[j].z, dQ[j].w};
            const int ss[4] = {sQ[j].x, sQ[j].y, sQ[j].z, sQ[j].w};
#pragma unroll
            for (int k = 0; k < 4; ++k) {
                const unsigned b = (unsigned)dd[k] >> BIN_SHIFT;
                ent[q0 + k] = ((unsigned)(dd[k] & (BIN_W - 1)) << NBITS_S)
                              | (unsigned)ss[k];
                bn[q0 + k]  = b;
                atomicAdd(&hist[b], 1u);
            }
        } else {
#pragma unroll
            for (int k = 0; k < 4; ++k) bn[q0 + k] = 0xFFu;
        }
    }
    __syncthreads();

    if (tid < 64) {
        unsigned h[4];
#pragma unroll
        for (int k = 0; k < 4; ++k) h[k] = hist[tid * 4 + k];
        const unsigned tot = h[0] + h[1] + h[2] + h[3];
        unsigned s = tot;
#pragma unroll
        for (int off = 1; off < 64; off <<= 1) {
            const unsigned y = __shfl_up(s, off);
            if (tid >= off) s += y;
        }
        unsigned run = s - tot;
#pragma unroll
        for (int k = 0; k < 4; ++k) {
            base[tid * 4 + k] = run;
            run += h[k];
        }
#pragma unroll
        for (int k = 0; k < 4; ++k)
            if (h[k]) gbase[tid * 4 + k] = atomicAdd(&cursor[tid * 4 + k], h[k]);
    }
    __syncthreads();

#pragma unroll
    for (int q = 0; q < EPT; ++q) {
        if (bn[q] != 0xFFu) {
            const unsigned b   = bn[q];
            const unsigned pos = base[b] + atomicAdd(&lcnt[b], 1u);
            sorted[pos] = ent[q];
            sbin[pos]   = (unsigned char)b;
        }
    }
    __syncthreads();

    for (int l = tid; l < nval; l += 256) {
        const unsigned b    = sbin[l];
        const unsigned gpos = gbase[b] + ((unsigned)l - base[b]);
        if (gpos < (b + 1u) * CAP)
            bins[gpos] = sorted[l];
    }
}

// ---- phase 2 (tier 1): gather table[src], pack, u64 LDS accumulate ----
__global__ __launch_bounds__(1024) void reduce_bins_tab(
        const float2* __restrict__ table, const unsigned* __restrict__ bins,
        const unsigned* __restrict__ cursor, const float* __restrict__ w0p,
        float* __restrict__ out, int N)
{
    __shared__ unsigned long long acc[BIN_W];           // 16 KB
    const int b     = blockIdx.x;
    const int tid   = threadIdx.x;
    const int node0 = b * BIN_W;
    const int W     = min(BIN_W, N - node0);

    for (int j = tid; j < BIN_W; j += 1024) acc[j] = 0ull;
    __syncthreads();

    const unsigned  base  = (unsigned)b * CAP;
    const int       count = (int)(cursor[b] - base);
    const unsigned* bp    = bins + base;

    const int CH = 1024 * 8;
    int i0 = 0;
    for (; i0 + CH <= count; i0 += CH) {
        const uint4_v ea = __builtin_nontemporal_load(
            (const uint4_v*)(bp + i0 + tid * 4));
        const uint4_v eb = __builtin_nontemporal_load(
            (const uint4_v*)(bp + i0 + 4096 + tid * 4));
        const unsigned ee[8] = {ea.x, ea.y, ea.z, ea.w, eb.x, eb.y, eb.z, eb.w};
        float2 ts[8];
#pragma unroll
        for (int k = 0; k < 8; ++k) ts[k] = table[ee[k] & SRC_MASK];
#pragma unroll
        for (int k = 0; k < 8; ++k) {
            const unsigned l  = ee[k] >> NBITS_S;
            const unsigned cq = (unsigned)__builtin_fmaf(ts[k].x, SCALE_F,
                                                         SCALE_F + 0.5f);
            const unsigned sq = (unsigned)__builtin_fmaf(ts[k].y, SCALE_F,
                                                         SCALE_F + 0.5f);
            atomicAdd(&acc[l], (1ull << 56) | ((unsigned long long)cq << 28)
                               | (unsigned long long)sq);
        }
    }
    for (int i = i0 + tid; i < count; i += 1024) {
        const unsigned e  = __builtin_nontemporal_load(bp + i);
        const unsigned l  = e >> NBITS_S;
        const float2  tsv = table[e & SRC_MASK];
        const unsigned cq = (unsigned)__builtin_fmaf(tsv.x, SCALE_F,
                                                     SCALE_F + 0.5f);
        const unsigned sq = (unsigned)__builtin_fmaf(tsv.y, SCALE_F,
                                                     SCALE_F + 0.5f);
        atomicAdd(&acc[l], (1ull << 56) | ((unsigned long long)cq << 28)
                           | (unsigned long long)sq);
    }
    __syncthreads();

    // epilogue: C,S per node; rotate by -td via table[node]; torque.
    const float w0 = *w0p;
    for (int j = tid; j < W; j += 1024) {
        const unsigned long long P = acc[j];
        const float c = (float)(unsigned)(P >> 56);
        const float C = (float)(unsigned)((P >> 28) & 0xFFFFFFFull) * INV_SCALE - c;
        const float S = (float)(unsigned)(P & 0xFFFFFFFull) * INV_SCALE - c;
        const float2 td = table[node0 + j];          // (cos td, sin td)
        const float nrm = sqrtf(C * C + S * S);
        out[2 * N + node0 + j] = w0 * ((td.x * S - td.y * C) / fmaxf(nrm, 1e-12f));
    }
}

// ================= tier 2: proven R5 pair (theta_q entries) =================

__global__ __launch_bounds__(256) void bin_edges_sort_thq(
        const float* __restrict__ theta,
        const int4* __restrict__ src4, const int4* __restrict__ dst4,
        unsigned* __restrict__ bins, unsigned* __restrict__ cursor, int E)
{
    __shared__ unsigned      sorted[K_BATCH];
    __shared__ unsigned char sbin[K_BATCH];
    __shared__ unsigned      hist[256];
    __shared__ unsigned      base[256];
    __shared__ unsigned      gbase[256];
    __shared__ unsigned      lcnt[256];

    const int tid   = threadIdx.x;
    const int bb    = blockIdx.x;
    const int e0    = bb * K_BATCH;
    const int nval  = min(K_BATCH, E - e0);
    const int E4    = E >> 2;
    const int base4 = e0 >> 2;

    hist[tid] = 0u;
    lcnt[tid] = 0u;
    __syncthreads();

    int4 sQ[EPT / 4];
#pragma unroll
    for (int j = 0; j < EPT / 4; ++j) {
        const int idx4 = base4 + j * 256 + tid;
        sQ[j] = (idx4 < E4) ? src4[idx4] : make_int4(0, 0, 0, 0);
    }
    float tq[EPT];
#pragma unroll
    for (int j = 0; j < EPT / 4; ++j) {
        tq[j * 4 + 0] = theta[sQ[j].x];
        tq[j * 4 + 1] = theta[sQ[j].y];
        tq[j * 4 + 2] = theta[sQ[j].z];
        tq[j * 4 + 3] = theta[sQ[j].w];
    }

    unsigned ent[EPT];
    unsigned bn[EPT];
#pragma unroll
    for (int j = 0; j < EPT / 4; ++j) {
        const int idx4 = base4 + j * 256 + tid;
        const int q0   = j * 4;
        if (idx4 < E4) {
            const int4 d = dst4[idx4];
            const int dd[4] = {d.x, d.y, d.z, d.w};
#pragma unroll
            for (int k = 0; k < 4; ++k) {
                const unsigned b = (unsigned)dd[k] >> BIN_SHIFT;
                float qf = (tq[q0 + k] + 8.0f) * Q_SCALE + 0.5f;
                qf = fminf(fmaxf(qf, 0.0f), 2097151.0f);
                ent[q0 + k] = ((unsigned)(dd[k] & (BIN_W - 1)) << NBITS_Q)
                              | (unsigned)qf;
                bn[q0 + k]  = b;
                atomicAdd(&hist[b], 1u);
            }
        } else {
#pragma unroll
            for (int k = 0; k < 4; ++k) bn[q0 + k] = 0xFFu;
        }
    }
    __syncthreads();

    if (tid < 64) {
        unsigned h[4];
#pragma unroll
        for (int k = 0; k < 4; ++k) h[k] = hist[tid * 4 + k];
        const unsigned tot = h[0] + h[1] + h[2] + h[3];
        unsigned s = tot;
#pragma unroll
        for (int off = 1; off < 64; off <<= 1) {
            const unsigned y = __shfl_up(s, off);
            if (tid >= off) s += y;
        }
        unsigned run = s - tot;
#pragma unroll
        for (int k = 0; k < 4; ++k) {
            base[tid * 4 + k] = run;
            run += h[k];
        }
#pragma unroll
        for (int k = 0; k < 4; ++k)
            if (h[k]) gbase[tid * 4 + k] = atomicAdd(&cursor[tid * 4 + k], h[k]);
    }
    __syncthreads();

#pragma unroll
    for (int q = 0; q < EPT; ++q) {
        if (bn[q] != 0xFFu) {
            const unsigned b   = bn[q];
            const unsigned pos = base[b] + atomicAdd(&lcnt[b], 1u);
            sorted[pos] = ent[q];
            sbin[pos]   = (unsigned char)b;
        }
    }
    __syncthreads();

    for (int l = tid; l < nval; l += 256) {
        const unsigned b    = sbin[l];
        const unsigned gpos = gbase[b] + ((unsigned)l - base[b]);
        if (gpos < (b + 1u) * CAP)
            bins[gpos] = sorted[l];
    }
}

__global__ __launch_bounds__(1024) void reduce_bins_thq(
        const float* __restrict__ theta, const unsigned* __restrict__ bins,
        const unsigned* __restrict__ cursor, const float* __restrict__ v0p,
        const float* __restrict__ w0p, float* __restrict__ out, int N)
{
    __shared__ float th[BIN_W];
    __shared__ unsigned long long acc[BIN_W];
    const int b     = blockIdx.x;
    const int tid   = threadIdx.x;
    const int node0 = b * BIN_W;
    const int W     = min(BIN_W, N - node0);

    for (int j = tid; j < BIN_W; j += 1024) {
        th[j]  = (j < W) ? theta[node0 + j] : 0.f;
        acc[j] = 0ull;
    }
    __syncthreads();

    const unsigned  base  = (unsigned)b * CAP;
    const int       count = (int)(cursor[b] - base);
    const unsigned* bp    = bins + base;

    const int CH = 1024 * 8;
    int i0 = 0;
    for (; i0 + CH <= count; i0 += CH) {
        const uint4_v ea = __builtin_nontemporal_load(
            (const uint4_v*)(bp + i0 + tid * 4));
        const uint4_v eb = __builtin_nontemporal_load(
            (const uint4_v*)(bp + i0 + 4096 + tid * 4));
        const unsigned ee[8] = {ea.x, ea.y, ea.z, ea.w, eb.x, eb.y, eb.z, eb.w};
#pragma unroll
        for (int k = 0; k < 8; ++k) {
            const unsigned e = ee[k];
            const unsigned l = e >> NBITS_Q;
            const float ts = (float)(e & Q_MASK) * Q_INV - 8.0f;
            const float r  = (ts - th[l]) * INV_2PI;
            const float sn = __builtin_amdgcn_sinf(r);
            const float cs = __builtin_amdgcn_cosf(r);
            const unsigned cq = (unsigned)((cs + 1.0f) * SCALE_F + 0.5f);
            const unsigned sq = (unsigned)((sn + 1.0f) * SCALE_F + 0.5f);
            atomicAdd(&acc[l], (1ull << 56) | ((unsigned long long)cq << 28)
                               | (unsigned long long)sq);
        }
    }
    for (int i = i0 + tid; i < count; i += 1024) {
        const unsigned e = __builtin_nontemporal_load(bp + i);
        const unsigned l = e >> NBITS_Q;
        const float ts = (float)(e & Q_MASK) * Q_INV - 8.0f;
        const float r  = (ts - th[l]) * INV_2PI;
        const float sn = __builtin_amdgcn_sinf(r);
        const float cs = __builtin_amdgcn_cosf(r);
        const unsigned cq = (unsigned)((cs + 1.0f) * SCALE_F + 0.5f);
        const unsigned sq = (unsigned)((sn + 1.0f) * SCALE_F + 0.5f);
        atomicAdd(&acc[l], (1ull << 56) | ((unsigned long long)cq << 28)
                           | (unsigned long long)sq);
    }
    __syncthreads();

    const float v0 = *v0p, w0 = *w0p;
    for (int j = tid; j < W; j += 1024) {
        const float t  = th[j];
        const float rr = t * INV_2PI;
        const float sn = __builtin_amdgcn_sinf(rr);
        const float cs = __builtin_amdgcn_cosf(rr);
        ((float2*)out)[node0 + j] = make_float2(v0 * cs, v0 * sn);
        const unsigned long long P = acc[j];
        const float c  = (float)(unsigned)(P >> 56);
        const float xs = (float)(unsigned)((P >> 28) & 0xFFFFFFFull) * INV_SCALE - c;
        const float ys = (float)(unsigned)(P & 0xFFFFFFFull) * INV_SCALE - c;
        const float nrm = sqrtf(xs * xs + ys * ys);
        out[2 * N + node0 + j] = w0 * (ys / fmaxf(nrm, 1e-12f));
    }
}

// ---------- tier 3: fallback (round-2 kernels) ----------

__global__ void zero_ws_kernel(float4* __restrict__ ws, int n4) {
    int i = blockIdx.x * blockDim.x + threadIdx.x;
    if (i < n4) ws[i] = make_float4(0.f, 0.f, 0.f, 0.f);
}

__global__ void edge_kernel_fb(const float* __restrict__ theta,
                               const int4* __restrict__ src4,
                               const int4* __restrict__ dst4,
                               float2* __restrict__ acc, int E8) {
    int i = blockIdx.x * blockDim.x + threadIdx.x;
    if (i >= E8) return;
    const int4 s0 = src4[2 * i], s1 = src4[2 * i + 1];
    const int4 d0 = dst4[2 * i], d1 = dst4[2 * i + 1];
    const int ss[8] = {s0.x, s0.y, s0.z, s0.w, s1.x, s1.y, s1.z, s1.w};
    const int dd[8] = {d0.x, d0.y, d0.z, d0.w, d1.x, d1.y, d1.z, d1.w};
    float ts[8], td[8];
#pragma unroll
    for (int k = 0; k < 8; ++k) ts[k] = theta[ss[k]];
#pragma unroll
    for (int k = 0; k < 8; ++k) td[k] = theta[dd[k]];
#pragma unroll
    for (int k = 0; k < 8; ++k) {
        float sn, cs;
        __sincosf(ts[k] - td[k], &sn, &cs);
        atomicAdd(&acc[dd[k]].x, cs);
        atomicAdd(&acc[dd[k]].y, sn);
    }
}

__global__ void node_kernel_fb(const float* __restrict__ theta,
                               const float2* __restrict__ acc,
                               const float* __restrict__ v0p,
                               const float* __restrict__ w0p,
                               float* __restrict__ out, int N) {
    int i = blockIdx.x * blockDim.x + threadIdx.x;
    if (i >= N) return;
    const float v0 = *v0p, w0 = *w0p;
    float sn, cs;
    __sincosf(theta[i], &sn, &cs);
    ((float2*)out)[i] = make_float2(v0 * cs, v0 * sn);
    const float2 a = acc[i];
    const float nrm = sqrtf(a.x * a.x + a.y * a.y);
    out[2 * N + i] = w0 * (a.y / fmaxf(nrm, 1e-12f));
}

extern "C" void kernel_launch(void* const* d_in, const int* in_sizes, int n_in,
                              void* d_out, int out_size, void* d_ws, size_t ws_size,
                              hipStream_t stream) {
    const float* theta = (const float*)d_in[0];
    const int*   src   = (const int*)d_in[1];
    const int*   dst   = (const int*)d_in[2];
    const float* v0p   = (const float*)d_in[3];
    const float* w0p   = (const float*)d_in[4];
    float*       out   = (float*)d_out;

    const int N = in_sizes[0];   // 500,000
    const int E = in_sizes[1];   // 16,000,000

    const size_t bins_bytes = (size_t)NB * CAP * sizeof(unsigned);
    const size_t tab_bytes  = (((size_t)N * 8) + 1023) & ~(size_t)1023;
    const size_t need_thq   = 1024 + bins_bytes;
    const size_t need_tab   = tab_bytes + 1024 + bins_bytes;

    const int nblk  = (E + K_BATCH - 1) / K_BATCH;   // 1954
    const int nbins = (N + BIN_W - 1) / BIN_W;       // 245

    if (ws_size >= need_tab && N <= NB * BIN_W && N <= (1 << NBITS_S)) {
        // tier 1: rotation-factored path
        float2*   table  = (float2*)d_ws;
        unsigned* cursor = (unsigned*)((char*)d_ws + tab_bytes);
        unsigned* bins   = cursor + 256;

        init_cursors<<<1, 256, 0, stream>>>(cursor);
        build_table<<<(N + 255) / 256, 256, 0, stream>>>(theta, v0p, table,
                                                         out, N);
        bin_edges_sort_src<<<nblk, 256, 0, stream>>>((const int4*)src,
                                                     (const int4*)dst,
                                                     bins, cursor, E);
        reduce_bins_tab<<<nbins, 1024, 0, stream>>>(table, bins, cursor,
                                                    w0p, out, N);
    } else if (ws_size >= need_thq && N <= NB * BIN_W) {
        // tier 2: proven R5 path
        unsigned* cursor = (unsigned*)d_ws;
        unsigned* bins   = cursor + 256;

        init_cursors<<<1, 256, 0, stream>>>(cursor);
        bin_edges_sort_thq<<<nblk, 256, 0, stream>>>(theta, (const int4*)src,
                                                     (const int4*)dst,
                                                     bins, cursor, E);
        reduce_bins_thq<<<nbins, 1024, 0, stream>>>(theta, bins, cursor,
                                                    v0p, w0p, out, N);
    } else {
        float2* acc = (float2*)d_ws;
        {
            const int n4 = (2 * N) / 4;
            zero_ws_kernel<<<(n4 + 255) / 256, 256, 0, stream>>>((float4*)d_ws, n4);
        }
        {
            const int E8 = E / 8;
            edge_kernel_fb<<<(E8 + 255) / 256, 256, 0, stream>>>(
                theta, (const int4*)src, (const int4*)dst, acc, E8);
        }
        node_kernel_fb<<<(N + 255) / 256, 256, 0, stream>>>(theta, acc, v0p, w0p,
                                                            out, N);
    }
}

// Round 7
// 268.225 us; speedup vs baseline: 1.6893x; 1.3268x over previous
//
#include <hip/hip_runtime.h>
#include <hip/hip_bf16.h>
#include <math.h>

// N=500,000 nodes, E=16,000,000 edges, D_COEF=1, EPS=1e-12.
// Outputs (fp32, flat): v [N,2] then torque [N,1].
// torque = w0 * sum_sin / max(||sum||, eps)  (count cancels in normalize).
//
// R5: theta_q in entry -> 264 us BEST (phase1=145, phase2=119).
// R6/R9/R10 FAILED: occupancy/pipeline experiments (codegen traps).
// R7/R11: gather is FREE in phase 1 (145 with == 168 without), costly
//     in phase 2 (+60-75 us). R8 FAILED: fewer LDS atomics, no change.
// => Phase-1 floor theory (R12): global cursor atomics. 245 counters
//     packed in ~16 cache lines; 1954 blocks RMW all of them =>
//     31,264 device-scope RMWs PER LINE, serialized at the coherence
//     point (~4.6ns each ~= 145 us). Explains R10's 2x regression
//     (3907 chunk-reservations -> 331 us) and why waves/atomics/gather
//     changes were all null (chain unchanged).
// R12: pad cursor to one counter per 64B line (stride 16 u32). Chain
//     per line 31,264 -> 1,954 RMWs (~9 us). Rest = R5/R8 verbatim.
//
// ws layout: uint cursor[256*CSTR] (16 KB), then uint bins[NB * CAP].

#define NBITS_Q   21
#define Q_MASK    ((1u << NBITS_Q) - 1)
#define Q_SCALE   131072.0f            // 2^21 / 16
#define Q_INV     (1.0f / 131072.0f)
#define BIN_SHIFT 11
#define BIN_W     2048
#define NB        245                  // ceil(500000/2048)
#define CAP       67584                // mean 65306 + ~9 sigma, mult of 4
#define K_BATCH   8192                 // edges per phase-1 block
#define EPT       32                   // edges per thread, phase 1
#define CSTR      16                   // cursor stride: 1 counter / 64B line
#define SCALE_F   524288.0f            // 2^19 (phase-2 fixed-point)
#define INV_SCALE (1.0f / 524288.0f)
#define INV_2PI   0.15915494309189535f

typedef unsigned uint4_v __attribute__((ext_vector_type(4)));

__global__ void init_cursors(unsigned* __restrict__ cur, int cstride) {
    const int tid = threadIdx.x;
    for (int i = tid; i < 256 * CSTR; i += 256) cur[i] = 0u;
    __syncthreads();
    if (tid < NB) cur[tid * cstride] = (unsigned)tid * CAP;
}

__global__ __launch_bounds__(256) void bin_edges_sort(
        const float* __restrict__ theta,
        const int4* __restrict__ src4, const int4* __restrict__ dst4,
        unsigned* __restrict__ bins, unsigned* __restrict__ cursor,
        int E, int cstride)
{
    __shared__ unsigned      sorted[K_BATCH];   // 32 KB
    __shared__ unsigned char sbin[K_BATCH];     //  8 KB
    __shared__ unsigned      hist[256];
    __shared__ unsigned      base[256];
    __shared__ unsigned      gbase[256];
    __shared__ unsigned      lcnt[256];

    const int tid   = threadIdx.x;
    const int bb    = blockIdx.x;
    const int e0    = bb * K_BATCH;
    const int nval  = min(K_BATCH, E - e0);
    const int E4    = E >> 2;
    const int base4 = e0 >> 2;

    hist[tid] = 0u;
    lcnt[tid] = 0u;
    __syncthreads();

    // ---- A: load all src quads, then issue all 32 theta gathers (MLP) ----
    int4 sQ[EPT / 4];
#pragma unroll
    for (int j = 0; j < EPT / 4; ++j) {
        const int idx4 = base4 + j * 256 + tid;
        sQ[j] = (idx4 < E4) ? src4[idx4] : make_int4(0, 0, 0, 0);
    }
    float tq[EPT];
#pragma unroll
    for (int j = 0; j < EPT / 4; ++j) {
        tq[j * 4 + 0] = theta[sQ[j].x];
        tq[j * 4 + 1] = theta[sQ[j].y];
        tq[j * 4 + 2] = theta[sQ[j].z];
        tq[j * 4 + 3] = theta[sQ[j].w];
    }

    // ---- B: load dst quads, build entries, histogram ----
    unsigned ent[EPT];
    unsigned bn[EPT];          // bin id, 0xFF = invalid
#pragma unroll
    for (int j = 0; j < EPT / 4; ++j) {
        const int idx4 = base4 + j * 256 + tid;
        const int q0   = j * 4;
        if (idx4 < E4) {
            const int4 d = dst4[idx4];
            const int dd[4] = {d.x, d.y, d.z, d.w};
#pragma unroll
            for (int k = 0; k < 4; ++k) {
                const unsigned b = (unsigned)dd[k] >> BIN_SHIFT;
                float qf = (tq[q0 + k] + 8.0f) * Q_SCALE + 0.5f;
                qf = fminf(fmaxf(qf, 0.0f), 2097151.0f);
                ent[q0 + k] = ((unsigned)(dd[k] & (BIN_W - 1)) << NBITS_Q)
                              | (unsigned)qf;
                bn[q0 + k]  = b;
                atomicAdd(&hist[b], 1u);
            }
        } else {
#pragma unroll
            for (int k = 0; k < 4; ++k) bn[q0 + k] = 0xFFu;
        }
    }
    __syncthreads();

    // ---- C: exclusive prefix scan of hist, single wave (lane owns 4 bins)
    if (tid < 64) {
        unsigned h[4];
#pragma unroll
        for (int k = 0; k < 4; ++k) h[k] = hist[tid * 4 + k];
        const unsigned tot = h[0] + h[1] + h[2] + h[3];
        unsigned s = tot;
#pragma unroll
        for (int off = 1; off < 64; off <<= 1) {
            const unsigned y = __shfl_up(s, off);
            if (tid >= off) s += y;
        }
        unsigned run = s - tot;              // exclusive across lanes
#pragma unroll
        for (int k = 0; k < 4; ++k) {
            base[tid * 4 + k] = run;
            run += h[k];
        }
#pragma unroll
        for (int k = 0; k < 4; ++k)
            if (h[k]) gbase[tid * 4 + k] =
                atomicAdd(&cursor[(tid * 4 + k) * cstride], h[k]);
    }
    __syncthreads();

    // ---- D: scatter into sorted LDS buffer ----
#pragma unroll
    for (int q = 0; q < EPT; ++q) {
        if (bn[q] != 0xFFu) {
            const unsigned b   = bn[q];
            const unsigned pos = base[b] + atomicAdd(&lcnt[b], 1u);
            sorted[pos] = ent[q];
            sbin[pos]   = (unsigned char)b;
        }
    }
    __syncthreads();

    // ---- E: coalesced write-out (contiguous run per bin) ----
    for (int l = tid; l < nval; l += 256) {
        const unsigned b    = sbin[l];
        const unsigned gpos = gbase[b] + ((unsigned)l - base[b]);
        if (gpos < (b + 1u) * CAP)          // ~9-sigma overflow guard
            bins[gpos] = sorted[l];
    }
}

__global__ __launch_bounds__(1024) void reduce_bins(
        const float* __restrict__ theta, const unsigned* __restrict__ bins,
        const unsigned* __restrict__ cursor, const float* __restrict__ v0p,
        const float* __restrict__ w0p, float* __restrict__ out,
        int N, int cstride)
{
    __shared__ float th[BIN_W];                         //  8 KB
    __shared__ unsigned long long acc[BIN_W];           // 16 KB
    const int b     = blockIdx.x;
    const int tid   = threadIdx.x;
    const int node0 = b * BIN_W;
    const int W     = min(BIN_W, N - node0);

    for (int j = tid; j < BIN_W; j += 1024) {
        th[j]  = (j < W) ? theta[node0 + j] : 0.f;
        acc[j] = 0ull;
    }
    __syncthreads();

    const unsigned  base  = (unsigned)b * CAP;
    const int       count = (int)(cursor[b * cstride] - base);
    const unsigned* bp    = bins + base;

    // stream 8 entries/thread/iter via two unit-stride nontemporal uint4 loads
    const int CH = 1024 * 8;
    int i0 = 0;
    for (; i0 + CH <= count; i0 += CH) {
        const uint4_v ea = __builtin_nontemporal_load(
            (const uint4_v*)(bp + i0 + tid * 4));
        const uint4_v eb = __builtin_nontemporal_load(
            (const uint4_v*)(bp + i0 + 4096 + tid * 4));
        const unsigned ee[8] = {ea.x, ea.y, ea.z, ea.w, eb.x, eb.y, eb.z, eb.w};
#pragma unroll
        for (int k = 0; k < 8; ++k) {
            const unsigned e = ee[k];
            const unsigned l = e >> NBITS_Q;
            const float ts = (float)(e & Q_MASK) * Q_INV - 8.0f;
            const float r  = (ts - th[l]) * INV_2PI;
            const float sn = __builtin_amdgcn_sinf(r);
            const float cs = __builtin_amdgcn_cosf(r);
            const unsigned cq = (unsigned)((cs + 1.0f) * SCALE_F + 0.5f);
            const unsigned sq = (unsigned)((sn + 1.0f) * SCALE_F + 0.5f);
            atomicAdd(&acc[l], (1ull << 56) | ((unsigned long long)cq << 28)
                               | (unsigned long long)sq);
        }
    }
    for (int i = i0 + tid; i < count; i += 1024) {
        const unsigned e = __builtin_nontemporal_load(bp + i);
        const unsigned l = e >> NBITS_Q;
        const float ts = (float)(e & Q_MASK) * Q_INV - 8.0f;
        const float r  = (ts - th[l]) * INV_2PI;
        const float sn = __builtin_amdgcn_sinf(r);
        const float cs = __builtin_amdgcn_cosf(r);
        const unsigned cq = (unsigned)((cs + 1.0f) * SCALE_F + 0.5f);
        const unsigned sq = (unsigned)((sn + 1.0f) * SCALE_F + 0.5f);
        atomicAdd(&acc[l], (1ull << 56) | ((unsigned long long)cq << 28)
                           | (unsigned long long)sq);
    }
    __syncthreads();

    // epilogue: unpack, v and torque (th[] is exact fp32 theta)
    const float v0 = *v0p, w0 = *w0p;
    for (int j = tid; j < W; j += 1024) {
        const float t  = th[j];
        const float rr = t * INV_2PI;
        const float sn = __builtin_amdgcn_sinf(rr);
        const float cs = __builtin_amdgcn_cosf(rr);
        ((float2*)out)[node0 + j] = make_float2(v0 * cs, v0 * sn);
        const unsigned long long P = acc[j];
        const float c  = (float)(unsigned)(P >> 56);
        const float xs = (float)(unsigned)((P >> 28) & 0xFFFFFFFull) * INV_SCALE - c;
        const float ys = (float)(unsigned)(P & 0xFFFFFFFull) * INV_SCALE - c;
        const float nrm = sqrtf(xs * xs + ys * ys);
        out[2 * N + node0 + j] = w0 * (ys / fmaxf(nrm, 1e-12f));
    }
}

// ---------- fallback path (round-2 kernels) if ws is too small ----------

__global__ void zero_ws_kernel(float4* __restrict__ ws, int n4) {
    int i = blockIdx.x * blockDim.x + threadIdx.x;
    if (i < n4) ws[i] = make_float4(0.f, 0.f, 0.f, 0.f);
}

__global__ void edge_kernel_fb(const float* __restrict__ theta,
                               const int4* __restrict__ src4,
                               const int4* __restrict__ dst4,
                               float2* __restrict__ acc, int E8) {
    int i = blockIdx.x * blockDim.x + threadIdx.x;
    if (i >= E8) return;
    const int4 s0 = src4[2 * i], s1 = src4[2 * i + 1];
    const int4 d0 = dst4[2 * i], d1 = dst4[2 * i + 1];
    const int ss[8] = {s0.x, s0.y, s0.z, s0.w, s1.x, s1.y, s1.z, s1.w};
    const int dd[8] = {d0.x, d0.y, d0.z, d0.w, d1.x, d1.y, d1.z, d1.w};
    float ts[8], td[8];
#pragma unroll
    for (int k = 0; k < 8; ++k) ts[k] = theta[ss[k]];
#pragma unroll
    for (int k = 0; k < 8; ++k) td[k] = theta[dd[k]];
#pragma unroll
    for (int k = 0; k < 8; ++k) {
        float sn, cs;
        __sincosf(ts[k] - td[k], &sn, &cs);
        atomicAdd(&acc[dd[k]].x, cs);
        atomicAdd(&acc[dd[k]].y, sn);
    }
}

__global__ void node_kernel_fb(const float* __restrict__ theta,
                               const float2* __restrict__ acc,
                               const float* __restrict__ v0p,
                               const float* __restrict__ w0p,
                               float* __restrict__ out, int N) {
    int i = blockIdx.x * blockDim.x + threadIdx.x;
    if (i >= N) return;
    const float v0 = *v0p, w0 = *w0p;
    float sn, cs;
    __sincosf(theta[i], &sn, &cs);
    ((float2*)out)[i] = make_float2(v0 * cs, v0 * sn);
    const float2 a = acc[i];
    const float nrm = sqrtf(a.x * a.x + a.y * a.y);
    out[2 * N + i] = w0 * (a.y / fmaxf(nrm, 1e-12f));
}

extern "C" void kernel_launch(void* const* d_in, const int* in_sizes, int n_in,
                              void* d_out, int out_size, void* d_ws, size_t ws_size,
                              hipStream_t stream) {
    const float* theta = (const float*)d_in[0];
    const int*   src   = (const int*)d_in[1];
    const int*   dst   = (const int*)d_in[2];
    const float* v0p   = (const float*)d_in[3];
    const float* w0p   = (const float*)d_in[4];
    float*       out   = (float*)d_out;

    const int N = in_sizes[0];   // 500,000
    const int E = in_sizes[1];   // 16,000,000

    const size_t bins_bytes = (size_t)NB * CAP * sizeof(unsigned);
    const size_t need_pad   = (size_t)256 * CSTR * 4 + bins_bytes;  // +16 KB
    const size_t need_min   = 1024 + bins_bytes;

    const int nblk  = (E + K_BATCH - 1) / K_BATCH;   // 1954
    const int nbins = (N + BIN_W - 1) / BIN_W;       // 245

    if (ws_size >= need_pad && N <= NB * BIN_W) {
        // tier 1: padded cursor (1 counter per 64B line)
        unsigned* cursor = (unsigned*)d_ws;
        unsigned* bins   = cursor + 256 * CSTR;

        init_cursors<<<1, 256, 0, stream>>>(cursor, CSTR);
        bin_edges_sort<<<nblk, 256, 0, stream>>>(theta, (const int4*)src,
                                                 (const int4*)dst,
                                                 bins, cursor, E, CSTR);
        reduce_bins<<<nbins, 1024, 0, stream>>>(theta, bins, cursor,
                                                v0p, w0p, out, N, CSTR);
    } else if (ws_size >= need_min && N <= NB * BIN_W) {
        // tier 2: packed cursor (proven R5 layout)
        unsigned* cursor = (unsigned*)d_ws;
        unsigned* bins   = cursor + 256;

        init_cursors<<<1, 256, 0, stream>>>(cursor, 1);
        bin_edges_sort<<<nblk, 256, 0, stream>>>(theta, (const int4*)src,
                                                 (const int4*)dst,
                                                 bins, cursor, E, 1);
        reduce_bins<<<nbins, 1024, 0, stream>>>(theta, bins, cursor,
                                                v0p, w0p, out, N, 1);
    } else {
        float2* acc = (float2*)d_ws;
        {
            const int n4 = (2 * N) / 4;
            zero_ws_kernel<<<(n4 + 255) / 256, 256, 0, stream>>>((float4*)d_ws, n4);
        }
        {
            const int E8 = E / 8;
            edge_kernel_fb<<<(E8 + 255) / 256, 256, 0, stream>>>(
                theta, (const int4*)src, (const int4*)dst, acc, E8);
        }
        node_kernel_fb<<<(N + 255) / 256, 256, 0, stream>>>(theta, acc, v0p, w0p,
                                                            out, N);
    }
}